// Round 11
// baseline (295.712 us; speedup 1.0000x reference)
//
#include <hip/hip_runtime.h>
#include <hip/hip_fp16.h>

#define DF 64
#define MSG 20
#define HID2 10
#define NODES 50000
#define EDGES 800000
#define GRAPHS 512
#define RSTRIDE 32   // halves per padded output row = 64 B (one cache line)
#define NB1 ((NODES + 255) / 256)   // 196
#define WR2 12       // half2 per W row in LDS (10 data + 2 pad) = 48 B

// 20 FMAs: acc[0..19] += xv * wr[0..19] (wr points into LDS, 16B-aligned)
#define FMA20(acc, xv, wr) do { \
  float4 w0_ = *(const float4*)((wr) + 0);  float4 w1_ = *(const float4*)((wr) + 4); \
  float4 w2_ = *(const float4*)((wr) + 8);  float4 w3_ = *(const float4*)((wr) + 12); \
  float4 w4_ = *(const float4*)((wr) + 16); \
  acc[0]=fmaf(xv,w0_.x,acc[0]);  acc[1]=fmaf(xv,w0_.y,acc[1]);  acc[2]=fmaf(xv,w0_.z,acc[2]);  acc[3]=fmaf(xv,w0_.w,acc[3]); \
  acc[4]=fmaf(xv,w1_.x,acc[4]);  acc[5]=fmaf(xv,w1_.y,acc[5]);  acc[6]=fmaf(xv,w1_.z,acc[6]);  acc[7]=fmaf(xv,w1_.w,acc[7]); \
  acc[8]=fmaf(xv,w2_.x,acc[8]);  acc[9]=fmaf(xv,w2_.y,acc[9]);  acc[10]=fmaf(xv,w2_.z,acc[10]); acc[11]=fmaf(xv,w2_.w,acc[11]); \
  acc[12]=fmaf(xv,w3_.x,acc[12]); acc[13]=fmaf(xv,w3_.y,acc[13]); acc[14]=fmaf(xv,w3_.z,acc[14]); acc[15]=fmaf(xv,w3_.w,acc[15]); \
  acc[16]=fmaf(xv,w4_.x,acc[16]); acc[17]=fmaf(xv,w4_.y,acc[17]); acc[18]=fmaf(xv,w4_.z,acc[18]); acc[19]=fmaf(xv,w4_.w,acc[19]); \
} while (0)

__global__ __launch_bounds__(256) void zero2_kernel(int* __restrict__ cnt, float* __restrict__ g) {
    int i = blockIdx.x * 256 + threadIdx.x;
    int st = gridDim.x * 256;
    for (int k = i; k < NODES; k += st) cnt[k] = 0;
    for (int k = i; k < GRAPHS * HID2; k += st) g[k] = 0.0f;
}

__global__ __launch_bounds__(256) void count_kernel(const int* __restrict__ ei, int* __restrict__ cnt) {
    int e = blockIdx.x * 256 + threadIdx.x;
    if (e < EDGES) atomicAdd(&cnt[ei[EDGES + e]], 1);
}

// Block-wise exclusive scan (Hillis-Steele in LDS).
__global__ __launch_bounds__(256) void scan_block(const int* __restrict__ in, int* __restrict__ outx,
                                                  int* __restrict__ bsum, int n) {
    __shared__ int s[256];
    int t = threadIdx.x, i = blockIdx.x * 256 + t;
    int v = (i < n) ? in[i] : 0;
    s[t] = v; __syncthreads();
    for (int off = 1; off < 256; off <<= 1) {
        int x = (t >= off) ? s[t - off] : 0;
        __syncthreads();
        s[t] += x; __syncthreads();
    }
    if (i < n) outx[i] = s[t] - v;
    if (t == 255 && bsum != nullptr) bsum[blockIdx.x] = s[255];
}

__device__ __forceinline__ void store_row_h(__half* dst, const float* acc) {
    union { __half2 h2[16]; uint4 q[4]; } u;
#pragma unroll
    for (int i = 0; i < 10; ++i) u.h2[i] = __floats2half2_rn(acc[2 * i], acc[2 * i + 1]);
#pragma unroll
    for (int i = 10; i < 16; ++i) u.h2[i] = __floats2half2_rn(0.0f, 0.0f);
    uint4* po = (uint4*)dst;
    po[0] = u.q[0]; po[1] = u.q[1]; po[2] = u.q[2]; po[3] = u.q[3];
}

// Fused: scan fixup (rs += bscan, cur = rs) AND pn projections (same 196x256 grid).
__global__ __launch_bounds__(256) void fixup_pn_kernel(int* __restrict__ rs, int* __restrict__ cur,
                                                       const int* __restrict__ bscan,
                                                       const float* __restrict__ node_attr,
                                                       const float* __restrict__ W,
                                                       __half* __restrict__ Ps, __half* __restrict__ Pd) {
    int i = blockIdx.x * 256 + threadIdx.x;
    if (i < NODES) {
        int r = rs[i] + bscan[blockIdx.x];
        rs[i] = r;
        cur[i] = r;
    }
    if (i == 0) rs[NODES] = EDGES;

    __shared__ float Wss[DF * MSG];
    __shared__ float Wds[DF * MSG];
    for (int k = threadIdx.x; k < DF * MSG; k += 256) {
        Wss[k] = W[k];
        Wds[k] = W[DF * MSG + k];
    }
    __syncthreads();

    int n = i;
    if (n >= NODES) return;

    const float4* nr = (const float4*)(node_attr + (size_t)n * DF);
    float4 x[16];
#pragma unroll
    for (int q = 0; q < 16; ++q) x[q] = nr[q];

    float as[MSG], ad[MSG];
#pragma unroll
    for (int j = 0; j < MSG; ++j) { as[j] = 0.0f; ad[j] = 0.0f; }

#pragma unroll
    for (int k4 = 0; k4 < 16; ++k4) {
        const float* xp = (const float*)&x[k4];
#pragma unroll
        for (int cc = 0; cc < 4; ++cc) {
            int k = k4 * 4 + cc;
            FMA20(as, xp[cc], &Wss[k * MSG]);
            FMA20(ad, xp[cc], &Wds[k * MSG]);
        }
    }

    store_row_h(Ps + (size_t)n * RSTRIDE, as);
    store_row_h(Pd + (size_t)n * RSTRIDE, ad);
}

__device__ __forceinline__ __half2 shflx_h2(__half2 v, int mask) {
    int x; __builtin_memcpy(&x, &v, 4);
    x = __shfl_xor(x, mask, 4);
    __half2 r; __builtin_memcpy(&r, &x, 4);
    return r;
}

// branchless 4-way select by q (0..3): avoids runtime-indexed register arrays
__device__ __forceinline__ __half2 sel4(int q, __half2 a, __half2 b, __half2 c, __half2 d) {
    __half2 ab = (q & 1) ? b : a;
    __half2 cd = (q & 1) ? d : c;
    return (q & 2) ? cd : ab;
}

// Edge kernel v4 ("quad"): 4 lanes per edge, 4 edges per 4-lane group.
// - Reads: lane q reads float4 #(s*4+q) of each row -> every instruction covers
//   full 64B lines (m13 streaming pattern). No LDS staging, no barriers in loop.
// - W (fp16, LDS) read once per k, amortized over 4 edges.
// - Width-4 shfl_xor butterfly -> all lanes hold all 20 sums; sel4 picks the
//   16B quarter each lane writes. Ps gathered as 4x16B coalesced 64B rows.
// - CSR slot via one atomic per lane (its own edge), broadcast with __shfl.
__global__ __launch_bounds__(256, 4) void pe_quad_kernel(
    const int* __restrict__ ei,
    const float* __restrict__ edge_attr,
    const float* __restrict__ W, const float* __restrict__ b,
    const __half* __restrict__ Ps,
    int* __restrict__ cur,
    __half* __restrict__ PeP)
{
    __shared__ __half2 Wh2[64 * WR2];   // 3072 B
    __shared__ __half2 bh[16];

    const int t = threadIdx.x;
    const int q = t & 3;
    const int e0 = blockIdx.x * 256 + (t >> 2) * 4;   // group's first edge (grid exact: 3125*256=800K)

    // stage W_e rows as half2 (k 0..63, 12 half2/row incl pad)
    for (int i = t; i < 64 * WR2; i += 256) {
        int k = i / WR2, j = i - k * WR2;
        __half2 v = __floats2half2_rn(0.0f, 0.0f);
        if (j < 10) v = __floats2half2_rn(W[2 * DF * MSG + k * MSG + 2 * j],
                                          W[2 * DF * MSG + k * MSG + 2 * j + 1]);
        Wh2[i] = v;
    }
    if (t < 16) {
        __half2 v = __floats2half2_rn(0.0f, 0.0f);
        if (t < 10) v = __floats2half2_rn(b[2 * t], b[2 * t + 1]);
        bh[t] = v;
    }

    // per-lane edge for the atomic/gather phase
    const int eq = e0 + q;
    const int srcq = ei[eq];
    const int dstq = ei[EDGES + eq];

    // load this lane's k-quarter of 4 edge rows; convert to half2
    // lane q, chunk s -> float4 #(s*4+q) -> k in [16s+4q, 16s+4q+4)
    const float4* ea4 = (const float4*)edge_attr;
    __half2 xh[4][8];
#pragma unroll
    for (int i = 0; i < 4; ++i) {
        size_t rb = (size_t)(e0 + i) * 16 + q;
        float4 v0 = ea4[rb + 0];
        float4 v1 = ea4[rb + 4];
        float4 v2 = ea4[rb + 8];
        float4 v3 = ea4[rb + 12];
        xh[i][0] = __floats2half2_rn(v0.x, v0.y); xh[i][1] = __floats2half2_rn(v0.z, v0.w);
        xh[i][2] = __floats2half2_rn(v1.x, v1.y); xh[i][3] = __floats2half2_rn(v1.z, v1.w);
        xh[i][4] = __floats2half2_rn(v2.x, v2.y); xh[i][5] = __floats2half2_rn(v2.z, v2.w);
        xh[i][6] = __floats2half2_rn(v3.x, v3.y); xh[i][7] = __floats2half2_rn(v3.z, v3.w);
    }

    __syncthreads();   // Wh2/bh ready

    __half2 acc[4][10];
#pragma unroll
    for (int i = 0; i < 4; ++i)
#pragma unroll
        for (int j = 0; j < 10; ++j) acc[i][j] = __floats2half2_rn(0.0f, 0.0f);

    // compute: 16 k per lane; W row read once per k, used for 4 edges
#pragma unroll
    for (int s = 0; s < 4; ++s) {
#pragma unroll
        for (int d = 0; d < 2; ++d) {
#pragma unroll
            for (int lh = 0; lh < 2; ++lh) {
                int k = s * 16 + q * 4 + 2 * d + lh;
                const __half2* wr = Wh2 + k * WR2;
                __half2 wa[10];
#pragma unroll
                for (int j = 0; j < 10; ++j) wa[j] = wr[j];
#pragma unroll
                for (int i = 0; i < 4; ++i) {
                    __half2 xb = lh ? __high2half2(xh[i][s * 2 + d])
                                    : __low2half2(xh[i][s * 2 + d]);
#pragma unroll
                    for (int j = 0; j < 10; ++j)
                        acc[i][j] = __hfma2(xb, wa[j], acc[i][j]);
                }
            }
        }
    }

    // width-4 butterfly: all 4 lanes get full sums for all 4 edges
#pragma unroll
    for (int i = 0; i < 4; ++i)
#pragma unroll
        for (int j = 0; j < 10; ++j) {
            acc[i][j] = __hadd2(acc[i][j], shflx_h2(acc[i][j], 1));
            acc[i][j] = __hadd2(acc[i][j], shflx_h2(acc[i][j], 2));
        }

    // + bias (after reduce!)
#pragma unroll
    for (int i = 0; i < 4; ++i)
#pragma unroll
        for (int j = 0; j < 10; ++j) acc[i][j] = __hadd2(acc[i][j], bh[j]);

    // CSR slot: each lane atomics for its own edge, then broadcast per i
    int p = atomicAdd(&cur[dstq], 1);

    const __half2 hz = __floats2half2_rn(0.0f, 0.0f);
#pragma unroll
    for (int i = 0; i < 4; ++i) {
        int pi = __shfl(p, i, 4);
        int si = __shfl(srcq, i, 4);

        // lane q's quarter = output pairs q*4+c (c=0..3); pairs >=10 are zero
        __half2 o0 = sel4(q, acc[i][0], acc[i][4], acc[i][8], hz);
        __half2 o1 = sel4(q, acc[i][1], acc[i][5], acc[i][9], hz);
        __half2 o2 = sel4(q, acc[i][2], acc[i][6], hz,        hz);
        __half2 o3 = sel4(q, acc[i][3], acc[i][7], hz,        hz);

        // + Ps[si] quarter (coalesced 64B row gather across the 4 lanes)
        uint4 ps = *(const uint4*)(Ps + (size_t)si * RSTRIDE + q * 8);
        union { uint4 u; __half2 h[4]; } pu; pu.u = ps;
        union { uint4 u; __half2 h[4]; } ou;
        ou.h[0] = __hadd2(o0, pu.h[0]);
        ou.h[1] = __hadd2(o1, pu.h[1]);
        ou.h[2] = __hadd2(o2, pu.h[2]);
        ou.h[3] = __hadd2(o3, pu.h[3]);

        *(uint4*)(PeP + (size_t)pi * RSTRIDE + q * 8) = ou.u;
    }
}

// Node-centric aggregate v2: 16 lanes per node (one CSR row each, typical deg=16),
// 16 consecutive 64B rows = 1KB contiguous per group. acc += relu(row + Pd[node]);
// 4-step width-16 shfl butterfly; MLP computed redundantly on all 16 lanes
// (same wave cost as 1 lane, no divergence); lane 0 atomics into gacc.
// Grid: 3125 blocks = 12500 waves (4x round-10) for latency hiding.
__global__ __launch_bounds__(256) void agg_kernel(const int* __restrict__ rs,
                                                  const __half* __restrict__ PeP,
                                                  const __half* __restrict__ Pd,
                                                  const float* __restrict__ W1, const float* __restrict__ b1,
                                                  const float* __restrict__ W2, const float* __restrict__ b2,
                                                  const int* __restrict__ batch, float* __restrict__ gacc) {
    __shared__ float W1s[MSG * MSG], W2s[MSG * HID2], b1s[MSG], b2s[HID2];
    for (int i = threadIdx.x; i < MSG * MSG; i += 256) W1s[i] = W1[i];
    for (int i = threadIdx.x; i < MSG * HID2; i += 256) W2s[i] = W2[i];
    if (threadIdx.x < MSG) b1s[threadIdx.x] = b1[threadIdx.x];
    if (threadIdx.x < HID2) b2s[threadIdx.x] = b2[threadIdx.x];
    __syncthreads();

    int t = threadIdx.x;
    int node = blockIdx.x * 16 + (t >> 4);
    int lane = t & 15;

    float acc[MSG];
#pragma unroll
    for (int j = 0; j < MSG; ++j) acc[j] = 0.0f;

    if (node < NODES) {
        int s0 = rs[node];
        int deg = rs[node + 1] - s0;

        float pd[MSG];
        {
            const uint4* pr = (const uint4*)(Pd + (size_t)node * RSTRIDE);
            union { uint4 q; __half2 h2[4]; } a0, a1;
            union { uint2 q; __half2 h2[2]; } a2;
            a0.q = pr[0]; a1.q = pr[1]; a2.q = *(const uint2*)(pr + 2);
#pragma unroll
            for (int i = 0; i < 4; ++i) {
                float2 f = __half22float2(a0.h2[i]);
                pd[2 * i] = f.x; pd[2 * i + 1] = f.y;
            }
#pragma unroll
            for (int i = 0; i < 4; ++i) {
                float2 f = __half22float2(a1.h2[i]);
                pd[8 + 2 * i] = f.x; pd[9 + 2 * i] = f.y;
            }
#pragma unroll
            for (int i = 0; i < 2; ++i) {
                float2 f = __half22float2(a2.h2[i]);
                pd[16 + 2 * i] = f.x; pd[17 + 2 * i] = f.y;
            }
        }

        for (int i = lane; i < deg; i += 16) {
            const uint4* rp = (const uint4*)(PeP + (size_t)(s0 + i) * RSTRIDE);
            uint4 q0 = rp[0], q1 = rp[1];
            uint2 q2 = *(const uint2*)(rp + 2);
            union { uint4 q; __half2 h2[4]; } a0, a1;
            union { uint2 q; __half2 h2[2]; } a2;
            a0.q = q0; a1.q = q1; a2.q = q2;
#pragma unroll
            for (int k = 0; k < 4; ++k) {
                float2 f = __half22float2(a0.h2[k]);
                acc[2 * k]     += fmaxf(f.x + pd[2 * k], 0.0f);
                acc[2 * k + 1] += fmaxf(f.y + pd[2 * k + 1], 0.0f);
            }
#pragma unroll
            for (int k = 0; k < 4; ++k) {
                float2 f = __half22float2(a1.h2[k]);
                acc[8 + 2 * k] += fmaxf(f.x + pd[8 + 2 * k], 0.0f);
                acc[9 + 2 * k] += fmaxf(f.y + pd[9 + 2 * k], 0.0f);
            }
#pragma unroll
            for (int k = 0; k < 2; ++k) {
                float2 f = __half22float2(a2.h2[k]);
                acc[16 + 2 * k] += fmaxf(f.x + pd[16 + 2 * k], 0.0f);
                acc[17 + 2 * k] += fmaxf(f.y + pd[17 + 2 * k], 0.0f);
            }
        }
    }

    // width-16 butterfly: all 16 lanes end with the full per-node sums
#pragma unroll
    for (int j = 0; j < MSG; ++j) acc[j] += __shfl_xor(acc[j], 1, 16);
#pragma unroll
    for (int j = 0; j < MSG; ++j) acc[j] += __shfl_xor(acc[j], 2, 16);
#pragma unroll
    for (int j = 0; j < MSG; ++j) acc[j] += __shfl_xor(acc[j], 4, 16);
#pragma unroll
    for (int j = 0; j < MSG; ++j) acc[j] += __shfl_xor(acc[j], 8, 16);

    if (node < NODES) {
        // MLP redundantly on all 16 lanes (no divergence; same wave cost as 1 lane)
        float t1[MSG];
#pragma unroll
        for (int j = 0; j < MSG; ++j) t1[j] = b1s[j];
#pragma unroll
        for (int k = 0; k < MSG; ++k)
#pragma unroll
            for (int j = 0; j < MSG; ++j) t1[j] = fmaf(acc[k], W1s[k * MSG + j], t1[j]);
#pragma unroll
        for (int j = 0; j < MSG; ++j) t1[j] = fmaxf(t1[j], 0.0f);

        float t2[HID2];
#pragma unroll
        for (int m = 0; m < HID2; ++m) t2[m] = b2s[m];
#pragma unroll
        for (int k = 0; k < MSG; ++k)
#pragma unroll
            for (int m = 0; m < HID2; ++m) t2[m] = fmaf(t1[k], W2s[k * HID2 + m], t2[m]);

        if (lane == 0) {
            int g = batch[node];
            float* gr = gacc + (size_t)g * HID2;
#pragma unroll
            for (int m = 0; m < HID2; ++m) atomicAdd(gr + m, fmaxf(t2[m], 0.0f));
        }
    }
}

__global__ void graph_kernel(const float* __restrict__ gacc,
                             const float* __restrict__ W3, const float* __restrict__ b3,
                             const float* __restrict__ W4, const float* __restrict__ b4,
                             float* __restrict__ out) {
    int g = blockIdx.x * blockDim.x + threadIdx.x;
    if (g >= GRAPHS) return;

    float h[HID2];
#pragma unroll
    for (int m = 0; m < HID2; ++m) h[m] = gacc[(size_t)g * HID2 + m];

    float t[HID2];
#pragma unroll
    for (int j = 0; j < HID2; ++j) {
        float s = b3[j];
#pragma unroll
        for (int k = 0; k < HID2; ++k) s = fmaf(h[k], W3[k * HID2 + j], s);
        t[j] = fmaxf(s, 0.0f);
    }
    float s = b4[0];
#pragma unroll
    for (int k = 0; k < HID2; ++k) s = fmaf(t[k], W4[k], s);
    out[g] = s;
}

extern "C" void kernel_launch(void* const* d_in, const int* in_sizes, int n_in,
                              void* d_out, int out_size, void* d_ws, size_t ws_size,
                              hipStream_t stream) {
    const int*   ei        = (const int*)  d_in[0];
    const float* node_attr = (const float*)d_in[1];
    const float* edge_attr = (const float*)d_in[2];
    const int*   batch     = (const int*)  d_in[3];
    const float* W_mpl     = (const float*)d_in[4];
    const float* b_mpl     = (const float*)d_in[5];
    const float* W1        = (const float*)d_in[6];
    const float* b1        = (const float*)d_in[7];
    const float* W2        = (const float*)d_in[8];
    const float* b2        = (const float*)d_in[9];
    const float* W3        = (const float*)d_in[10];
    const float* b3        = (const float*)d_in[11];
    const float* W4        = (const float*)d_in[12];
    const float* b4        = (const float*)d_in[13];
    float* out = (float*)d_out;

    // workspace layout (all offsets multiples of 64B)
    __half* PeP = (__half*)d_ws;                          // E*32 halves (51.2 MB), CSR-ordered
    __half* Ps  = PeP + (size_t)EDGES * RSTRIDE;          // N*32 halves (3.2 MB)
    __half* Pd  = Ps + (size_t)NODES * RSTRIDE;           // N*32 halves (3.2 MB)
    float* gacc = (float*)(Pd + (size_t)NODES * RSTRIDE); // G*10
    int* cnt    = (int*)(gacc + GRAPHS * HID2);           // N (padded 50176)
    int* rs     = cnt + 50176;                            // N+1 (padded)
    int* cur    = rs + 50176;                             // N (padded)
    int* bsum   = cur + 50176;                            // 256
    int* bscan  = bsum + 256;                             // 256

    int egrid  = (EDGES + 255) / 256;   // 3125
    int ngrid  = NB1;                   // 196

    hipLaunchKernelGGL(zero2_kernel, dim3(256), dim3(256), 0, stream, cnt, gacc);
    hipLaunchKernelGGL(count_kernel, dim3(egrid), dim3(256), 0, stream, ei, cnt);
    hipLaunchKernelGGL(scan_block, dim3(ngrid), dim3(256), 0, stream, cnt, rs, bsum, NODES);
    hipLaunchKernelGGL(scan_block, dim3(1), dim3(256), 0, stream, bsum, bscan, (int*)nullptr, NB1);
    hipLaunchKernelGGL(fixup_pn_kernel, dim3(ngrid), dim3(256), 0, stream,
                       rs, cur, bscan, node_attr, W_mpl, Ps, Pd);
    hipLaunchKernelGGL(pe_quad_kernel, dim3(egrid), dim3(256), 0, stream,
                       ei, edge_attr, W_mpl, b_mpl, Ps, cur, PeP);
    hipLaunchKernelGGL(agg_kernel, dim3((NODES + 15) / 16), dim3(256), 0, stream,
                       rs, PeP, Pd, W1, b1, W2, b2, batch, gacc);
    hipLaunchKernelGGL(graph_kernel, dim3(2), dim3(256), 0, stream, gacc, W3, b3, W4, b4, out);
}

// Round 12
// 159.980 us; speedup vs baseline: 1.8484x; 1.8484x over previous
//
#include <hip/hip_runtime.h>
#include <hip/hip_fp16.h>

#define DF 64
#define MSG 20
#define HID2 10
#define NODES 50000
#define EDGES 800000
#define GRAPHS 512
#define RSTRIDE 32   // halves per padded PeP row = 64 B (one cache line)
#define RS2 12       // floats per padded x2 row = 48 B (16B-aligned)
#define NB1 ((NODES + 255) / 256)   // 196
#define WR2 12       // half2 per W row in LDS (10 data + 2 pad) = 48 B

// 20 FMAs: acc[0..19] += xv * wr[0..19] (wr points into LDS, 16B-aligned)
#define FMA20(acc, xv, wr) do { \
  float4 w0_ = *(const float4*)((wr) + 0);  float4 w1_ = *(const float4*)((wr) + 4); \
  float4 w2_ = *(const float4*)((wr) + 8);  float4 w3_ = *(const float4*)((wr) + 12); \
  float4 w4_ = *(const float4*)((wr) + 16); \
  acc[0]=fmaf(xv,w0_.x,acc[0]);  acc[1]=fmaf(xv,w0_.y,acc[1]);  acc[2]=fmaf(xv,w0_.z,acc[2]);  acc[3]=fmaf(xv,w0_.w,acc[3]); \
  acc[4]=fmaf(xv,w1_.x,acc[4]);  acc[5]=fmaf(xv,w1_.y,acc[5]);  acc[6]=fmaf(xv,w1_.z,acc[6]);  acc[7]=fmaf(xv,w1_.w,acc[7]); \
  acc[8]=fmaf(xv,w2_.x,acc[8]);  acc[9]=fmaf(xv,w2_.y,acc[9]);  acc[10]=fmaf(xv,w2_.z,acc[10]); acc[11]=fmaf(xv,w2_.w,acc[11]); \
  acc[12]=fmaf(xv,w3_.x,acc[12]); acc[13]=fmaf(xv,w3_.y,acc[13]); acc[14]=fmaf(xv,w3_.z,acc[14]); acc[15]=fmaf(xv,w3_.w,acc[15]); \
  acc[16]=fmaf(xv,w4_.x,acc[16]); acc[17]=fmaf(xv,w4_.y,acc[17]); acc[18]=fmaf(xv,w4_.z,acc[18]); acc[19]=fmaf(xv,w4_.w,acc[19]); \
} while (0)

__global__ __launch_bounds__(256) void zero_cnt_kernel(int* __restrict__ cnt) {
    int i = blockIdx.x * 256 + threadIdx.x;
    int st = gridDim.x * 256;
    for (int k = i; k < NODES; k += st) cnt[k] = 0;
}

__global__ __launch_bounds__(256) void count_kernel(const int* __restrict__ ei, int* __restrict__ cnt) {
    int e = blockIdx.x * 256 + threadIdx.x;
    if (e < EDGES) atomicAdd(&cnt[ei[EDGES + e]], 1);
}

// Block-wise exclusive scan (Hillis-Steele in LDS).
__global__ __launch_bounds__(256) void scan_block(const int* __restrict__ in, int* __restrict__ outx,
                                                  int* __restrict__ bsum, int n) {
    __shared__ int s[256];
    int t = threadIdx.x, i = blockIdx.x * 256 + t;
    int v = (i < n) ? in[i] : 0;
    s[t] = v; __syncthreads();
    for (int off = 1; off < 256; off <<= 1) {
        int x = (t >= off) ? s[t - off] : 0;
        __syncthreads();
        s[t] += x; __syncthreads();
    }
    if (i < n) outx[i] = s[t] - v;
    if (t == 255 && bsum != nullptr) bsum[blockIdx.x] = s[255];
}

__device__ __forceinline__ void store_row_h(__half* dst, const float* acc) {
    union { __half2 h2[16]; uint4 q[4]; } u;
#pragma unroll
    for (int i = 0; i < 10; ++i) u.h2[i] = __floats2half2_rn(acc[2 * i], acc[2 * i + 1]);
#pragma unroll
    for (int i = 10; i < 16; ++i) u.h2[i] = __floats2half2_rn(0.0f, 0.0f);
    uint4* po = (uint4*)dst;
    po[0] = u.q[0]; po[1] = u.q[1]; po[2] = u.q[2]; po[3] = u.q[3];
}

// Fused: scan fixup (rs += bscan, cur = rs) AND pn projections (same 196x256 grid).
__global__ __launch_bounds__(256) void fixup_pn_kernel(int* __restrict__ rs, int* __restrict__ cur,
                                                       const int* __restrict__ bscan,
                                                       const float* __restrict__ node_attr,
                                                       const float* __restrict__ W,
                                                       __half* __restrict__ Ps, __half* __restrict__ Pd) {
    int i = blockIdx.x * 256 + threadIdx.x;
    if (i < NODES) {
        int r = rs[i] + bscan[blockIdx.x];
        rs[i] = r;
        cur[i] = r;
    }
    if (i == 0) rs[NODES] = EDGES;

    __shared__ float Wss[DF * MSG];
    __shared__ float Wds[DF * MSG];
    for (int k = threadIdx.x; k < DF * MSG; k += 256) {
        Wss[k] = W[k];
        Wds[k] = W[DF * MSG + k];
    }
    __syncthreads();

    int n = i;
    if (n >= NODES) return;

    const float4* nr = (const float4*)(node_attr + (size_t)n * DF);
    float4 x[16];
#pragma unroll
    for (int q = 0; q < 16; ++q) x[q] = nr[q];

    float as[MSG], ad[MSG];
#pragma unroll
    for (int j = 0; j < MSG; ++j) { as[j] = 0.0f; ad[j] = 0.0f; }

#pragma unroll
    for (int k4 = 0; k4 < 16; ++k4) {
        const float* xp = (const float*)&x[k4];
#pragma unroll
        for (int cc = 0; cc < 4; ++cc) {
            int k = k4 * 4 + cc;
            FMA20(as, xp[cc], &Wss[k * MSG]);
            FMA20(ad, xp[cc], &Wds[k * MSG]);
        }
    }

    store_row_h(Ps + (size_t)n * RSTRIDE, as);
    store_row_h(Pd + (size_t)n * RSTRIDE, ad);
}

// batch is SORTED: graph g owns contiguous node range [gstart[g], gstart[g+1]).
__global__ __launch_bounds__(256) void gbounds_kernel(const int* __restrict__ batch,
                                                      int* __restrict__ gstart) {
    int i = blockIdx.x * 256 + threadIdx.x;
    if (i < NODES) {
        int b = batch[i];
        int bp = (i == 0) ? -1 : batch[i - 1];
        for (int g = bp + 1; g <= b; ++g) gstart[g] = i;
        if (i == NODES - 1) {
            for (int g = b + 1; g <= GRAPHS; ++g) gstart[g] = NODES;
        }
    }
}

__device__ __forceinline__ __half2 shflx_h2(__half2 v, int mask) {
    int x; __builtin_memcpy(&x, &v, 4);
    x = __shfl_xor(x, mask, 4);
    __half2 r; __builtin_memcpy(&r, &x, 4);
    return r;
}

// branchless 4-way select by q (0..3)
__device__ __forceinline__ __half2 sel4(int q, __half2 a, __half2 b, __half2 c, __half2 d) {
    __half2 ab = (q & 1) ? b : a;
    __half2 cd = (q & 1) ? d : c;
    return (q & 2) ? cd : ab;
}

// Edge kernel ("quad"): 4 lanes per edge, 4 edges per 4-lane group. (round-10, unchanged)
__global__ __launch_bounds__(256, 4) void pe_quad_kernel(
    const int* __restrict__ ei,
    const float* __restrict__ edge_attr,
    const float* __restrict__ W, const float* __restrict__ b,
    const __half* __restrict__ Ps,
    int* __restrict__ cur,
    __half* __restrict__ PeP)
{
    __shared__ __half2 Wh2[64 * WR2];   // 3072 B
    __shared__ __half2 bh[16];

    const int t = threadIdx.x;
    const int q = t & 3;
    const int e0 = blockIdx.x * 256 + (t >> 2) * 4;

    for (int i = t; i < 64 * WR2; i += 256) {
        int k = i / WR2, j = i - k * WR2;
        __half2 v = __floats2half2_rn(0.0f, 0.0f);
        if (j < 10) v = __floats2half2_rn(W[2 * DF * MSG + k * MSG + 2 * j],
                                          W[2 * DF * MSG + k * MSG + 2 * j + 1]);
        Wh2[i] = v;
    }
    if (t < 16) {
        __half2 v = __floats2half2_rn(0.0f, 0.0f);
        if (t < 10) v = __floats2half2_rn(b[2 * t], b[2 * t + 1]);
        bh[t] = v;
    }

    const int eq = e0 + q;
    const int srcq = ei[eq];
    const int dstq = ei[EDGES + eq];

    const float4* ea4 = (const float4*)edge_attr;
    __half2 xh[4][8];
#pragma unroll
    for (int i = 0; i < 4; ++i) {
        size_t rb = (size_t)(e0 + i) * 16 + q;
        float4 v0 = ea4[rb + 0];
        float4 v1 = ea4[rb + 4];
        float4 v2 = ea4[rb + 8];
        float4 v3 = ea4[rb + 12];
        xh[i][0] = __floats2half2_rn(v0.x, v0.y); xh[i][1] = __floats2half2_rn(v0.z, v0.w);
        xh[i][2] = __floats2half2_rn(v1.x, v1.y); xh[i][3] = __floats2half2_rn(v1.z, v1.w);
        xh[i][4] = __floats2half2_rn(v2.x, v2.y); xh[i][5] = __floats2half2_rn(v2.z, v2.w);
        xh[i][6] = __floats2half2_rn(v3.x, v3.y); xh[i][7] = __floats2half2_rn(v3.z, v3.w);
    }

    __syncthreads();

    __half2 acc[4][10];
#pragma unroll
    for (int i = 0; i < 4; ++i)
#pragma unroll
        for (int j = 0; j < 10; ++j) acc[i][j] = __floats2half2_rn(0.0f, 0.0f);

#pragma unroll
    for (int s = 0; s < 4; ++s) {
#pragma unroll
        for (int d = 0; d < 2; ++d) {
#pragma unroll
            for (int lh = 0; lh < 2; ++lh) {
                int k = s * 16 + q * 4 + 2 * d + lh;
                const __half2* wr = Wh2 + k * WR2;
                __half2 wa[10];
#pragma unroll
                for (int j = 0; j < 10; ++j) wa[j] = wr[j];
#pragma unroll
                for (int i = 0; i < 4; ++i) {
                    __half2 xb = lh ? __high2half2(xh[i][s * 2 + d])
                                    : __low2half2(xh[i][s * 2 + d]);
#pragma unroll
                    for (int j = 0; j < 10; ++j)
                        acc[i][j] = __hfma2(xb, wa[j], acc[i][j]);
                }
            }
        }
    }

#pragma unroll
    for (int i = 0; i < 4; ++i)
#pragma unroll
        for (int j = 0; j < 10; ++j) {
            acc[i][j] = __hadd2(acc[i][j], shflx_h2(acc[i][j], 1));
            acc[i][j] = __hadd2(acc[i][j], shflx_h2(acc[i][j], 2));
        }

#pragma unroll
    for (int i = 0; i < 4; ++i)
#pragma unroll
        for (int j = 0; j < 10; ++j) acc[i][j] = __hadd2(acc[i][j], bh[j]);

    int p = atomicAdd(&cur[dstq], 1);

    const __half2 hz = __floats2half2_rn(0.0f, 0.0f);
#pragma unroll
    for (int i = 0; i < 4; ++i) {
        int pi = __shfl(p, i, 4);
        int si = __shfl(srcq, i, 4);

        __half2 o0 = sel4(q, acc[i][0], acc[i][4], acc[i][8], hz);
        __half2 o1 = sel4(q, acc[i][1], acc[i][5], acc[i][9], hz);
        __half2 o2 = sel4(q, acc[i][2], acc[i][6], hz,        hz);
        __half2 o3 = sel4(q, acc[i][3], acc[i][7], hz,        hz);

        uint4 ps = *(const uint4*)(Ps + (size_t)si * RSTRIDE + q * 8);
        union { uint4 u; __half2 h[4]; } pu; pu.u = ps;
        union { uint4 u; __half2 h[4]; } ou;
        ou.h[0] = __hadd2(o0, pu.h[0]);
        ou.h[1] = __hadd2(o1, pu.h[1]);
        ou.h[2] = __hadd2(o2, pu.h[2]);
        ou.h[3] = __hadd2(o3, pu.h[3]);

        *(uint4*)(PeP + (size_t)pi * RSTRIDE + q * 8) = ou.u;
    }
}

// Node aggregate (round-10 base + 4-deep load batching + x2 store, no atomics):
// 4 lanes/node, loop stride 16 with 4 predicated row-loads in flight (12 loads).
// acc += relu(row + Pd[node]); 2-step shfl butterfly; lane 0 runs 20->20->10 MLP
// and stores relu result to x2[node] (48B padded row, streaming write).
__global__ __launch_bounds__(256, 4) void agg_kernel(const int* __restrict__ rs,
                                                     const __half* __restrict__ PeP,
                                                     const __half* __restrict__ Pd,
                                                     const float* __restrict__ W1, const float* __restrict__ b1,
                                                     const float* __restrict__ W2, const float* __restrict__ b2,
                                                     float* __restrict__ x2) {
    __shared__ float W1s[MSG * MSG], W2s[MSG * HID2], b1s[MSG], b2s[HID2];
    for (int i = threadIdx.x; i < MSG * MSG; i += 256) W1s[i] = W1[i];
    for (int i = threadIdx.x; i < MSG * HID2; i += 256) W2s[i] = W2[i];
    if (threadIdx.x < MSG) b1s[threadIdx.x] = b1[threadIdx.x];
    if (threadIdx.x < HID2) b2s[threadIdx.x] = b2[threadIdx.x];
    __syncthreads();

    int t = threadIdx.x;
    int node = blockIdx.x * 64 + (t >> 2);
    int lane = t & 3;

    float acc[MSG];
#pragma unroll
    for (int j = 0; j < MSG; ++j) acc[j] = 0.0f;

    if (node < NODES) {
        int s0 = rs[node];
        int deg = rs[node + 1] - s0;

        float pd[MSG];
        {
            const uint4* pr = (const uint4*)(Pd + (size_t)node * RSTRIDE);
            union { uint4 q; __half2 h2[4]; } a0, a1;
            union { uint2 q; __half2 h2[2]; } a2;
            a0.q = pr[0]; a1.q = pr[1]; a2.q = *(const uint2*)(pr + 2);
#pragma unroll
            for (int i = 0; i < 4; ++i) {
                float2 f = __half22float2(a0.h2[i]);
                pd[2 * i] = f.x; pd[2 * i + 1] = f.y;
            }
#pragma unroll
            for (int i = 0; i < 4; ++i) {
                float2 f = __half22float2(a1.h2[i]);
                pd[8 + 2 * i] = f.x; pd[9 + 2 * i] = f.y;
            }
#pragma unroll
            for (int i = 0; i < 2; ++i) {
                float2 f = __half22float2(a2.h2[i]);
                pd[16 + 2 * i] = f.x; pd[17 + 2 * i] = f.y;
            }
        }

        for (int i0 = lane; i0 < deg; i0 += 16) {
            // issue up to 12 loads (4 rows x 3) before consuming
            uint4 qa[4], qb[4]; uint2 qc[4]; int vm[4];
#pragma unroll
            for (int u = 0; u < 4; ++u) {
                int i = i0 + 4 * u;
                vm[u] = (i < deg);
                if (vm[u]) {
                    const uint4* rp = (const uint4*)(PeP + (size_t)(s0 + i) * RSTRIDE);
                    qa[u] = rp[0]; qb[u] = rp[1]; qc[u] = *(const uint2*)(rp + 2);
                }
            }
#pragma unroll
            for (int u = 0; u < 4; ++u) {
                if (!vm[u]) continue;
                union { uint4 q; __half2 h2[4]; } a0, a1;
                union { uint2 q; __half2 h2[2]; } a2;
                a0.q = qa[u]; a1.q = qb[u]; a2.q = qc[u];
#pragma unroll
                for (int k = 0; k < 4; ++k) {
                    float2 f = __half22float2(a0.h2[k]);
                    acc[2 * k]     += fmaxf(f.x + pd[2 * k], 0.0f);
                    acc[2 * k + 1] += fmaxf(f.y + pd[2 * k + 1], 0.0f);
                }
#pragma unroll
                for (int k = 0; k < 4; ++k) {
                    float2 f = __half22float2(a1.h2[k]);
                    acc[8 + 2 * k] += fmaxf(f.x + pd[8 + 2 * k], 0.0f);
                    acc[9 + 2 * k] += fmaxf(f.y + pd[9 + 2 * k], 0.0f);
                }
#pragma unroll
                for (int k = 0; k < 2; ++k) {
                    float2 f = __half22float2(a2.h2[k]);
                    acc[16 + 2 * k] += fmaxf(f.x + pd[16 + 2 * k], 0.0f);
                    acc[17 + 2 * k] += fmaxf(f.y + pd[17 + 2 * k], 0.0f);
                }
            }
        }
    }

#pragma unroll
    for (int j = 0; j < MSG; ++j) acc[j] += __shfl_xor(acc[j], 1);
#pragma unroll
    for (int j = 0; j < MSG; ++j) acc[j] += __shfl_xor(acc[j], 2);

    if (node < NODES && lane == 0) {
        float t1[MSG];
#pragma unroll
        for (int j = 0; j < MSG; ++j) t1[j] = b1s[j];
#pragma unroll
        for (int k = 0; k < MSG; ++k)
#pragma unroll
            for (int j = 0; j < MSG; ++j) t1[j] = fmaf(acc[k], W1s[k * MSG + j], t1[j]);
#pragma unroll
        for (int j = 0; j < MSG; ++j) t1[j] = fmaxf(t1[j], 0.0f);

        float t2[HID2];
#pragma unroll
        for (int m = 0; m < HID2; ++m) t2[m] = b2s[m];
#pragma unroll
        for (int k = 0; k < MSG; ++k)
#pragma unroll
            for (int m = 0; m < HID2; ++m) t2[m] = fmaf(t1[k], W2s[k * HID2 + m], t2[m]);

        float* xo = x2 + (size_t)node * RS2;
        *(float4*)(xo)     = make_float4(fmaxf(t2[0], 0.f), fmaxf(t2[1], 0.f), fmaxf(t2[2], 0.f), fmaxf(t2[3], 0.f));
        *(float4*)(xo + 4) = make_float4(fmaxf(t2[4], 0.f), fmaxf(t2[5], 0.f), fmaxf(t2[6], 0.f), fmaxf(t2[7], 0.f));
        *(float4*)(xo + 8) = make_float4(fmaxf(t2[8], 0.f), fmaxf(t2[9], 0.f), 0.f, 0.f);
    }
}

// Graph reduce v2: one 64-thread wave per graph streams its CONTIGUOUS x2 segment
// (batch sorted -> no atomics), shfl-reduces, lane 0 runs 10->10->1 head.
__global__ __launch_bounds__(64) void graph2_kernel(const int* __restrict__ gstart,
                                                    const float* __restrict__ x2,
                                                    const float* __restrict__ W3, const float* __restrict__ b3,
                                                    const float* __restrict__ W4, const float* __restrict__ b4,
                                                    float* __restrict__ out) {
    int g = blockIdx.x;
    int lane = threadIdx.x;
    int n0 = gstart[g], n1 = gstart[g + 1];

    float acc[HID2];
#pragma unroll
    for (int j = 0; j < HID2; ++j) acc[j] = 0.0f;

    for (int i = n0 + lane; i < n1; i += 64) {
        const float* xr = x2 + (size_t)i * RS2;
        float4 v0 = *(const float4*)xr;
        float4 v1 = *(const float4*)(xr + 4);
        float2 v2 = *(const float2*)(xr + 8);
        acc[0] += v0.x; acc[1] += v0.y; acc[2] += v0.z; acc[3] += v0.w;
        acc[4] += v1.x; acc[5] += v1.y; acc[6] += v1.z; acc[7] += v1.w;
        acc[8] += v2.x; acc[9] += v2.y;
    }

#pragma unroll
    for (int m = 1; m < 64; m <<= 1)
#pragma unroll
        for (int j = 0; j < HID2; ++j) acc[j] += __shfl_xor(acc[j], m);

    if (lane == 0) {
        float tt[HID2];
#pragma unroll
        for (int j = 0; j < HID2; ++j) {
            float s = b3[j];
#pragma unroll
            for (int k = 0; k < HID2; ++k) s = fmaf(acc[k], W3[k * HID2 + j], s);
            tt[j] = fmaxf(s, 0.0f);
        }
        float s = b4[0];
#pragma unroll
        for (int k = 0; k < HID2; ++k) s = fmaf(tt[k], W4[k], s);
        out[g] = s;
    }
}

extern "C" void kernel_launch(void* const* d_in, const int* in_sizes, int n_in,
                              void* d_out, int out_size, void* d_ws, size_t ws_size,
                              hipStream_t stream) {
    const int*   ei        = (const int*)  d_in[0];
    const float* node_attr = (const float*)d_in[1];
    const float* edge_attr = (const float*)d_in[2];
    const int*   batch     = (const int*)  d_in[3];
    const float* W_mpl     = (const float*)d_in[4];
    const float* b_mpl     = (const float*)d_in[5];
    const float* W1        = (const float*)d_in[6];
    const float* b1        = (const float*)d_in[7];
    const float* W2        = (const float*)d_in[8];
    const float* b2        = (const float*)d_in[9];
    const float* W3        = (const float*)d_in[10];
    const float* b3        = (const float*)d_in[11];
    const float* W4        = (const float*)d_in[12];
    const float* b4        = (const float*)d_in[13];
    float* out = (float*)d_out;

    // workspace layout (all offsets multiples of 64B)
    __half* PeP = (__half*)d_ws;                          // E*32 halves (51.2 MB), CSR-ordered
    __half* Ps  = PeP + (size_t)EDGES * RSTRIDE;          // N*32 halves (3.2 MB)
    __half* Pd  = Ps + (size_t)NODES * RSTRIDE;           // N*32 halves (3.2 MB)
    float* x2   = (float*)(Pd + (size_t)NODES * RSTRIDE); // N*12 floats (2.4 MB)
    int* cnt    = (int*)(x2 + (size_t)NODES * RS2);       // N (padded 50176)
    int* rs     = cnt + 50176;                            // N+1 (padded)
    int* cur    = rs + 50176;                             // N (padded)
    int* bsum   = cur + 50176;                            // 256
    int* bscan  = bsum + 256;                             // 256
    int* gstart = bscan + 256;                            // G+1

    int egrid  = (EDGES + 255) / 256;   // 3125
    int ngrid  = NB1;                   // 196

    hipLaunchKernelGGL(zero_cnt_kernel, dim3(256), dim3(256), 0, stream, cnt);
    hipLaunchKernelGGL(count_kernel, dim3(egrid), dim3(256), 0, stream, ei, cnt);
    hipLaunchKernelGGL(scan_block, dim3(ngrid), dim3(256), 0, stream, cnt, rs, bsum, NODES);
    hipLaunchKernelGGL(scan_block, dim3(1), dim3(256), 0, stream, bsum, bscan, (int*)nullptr, NB1);
    hipLaunchKernelGGL(fixup_pn_kernel, dim3(ngrid), dim3(256), 0, stream,
                       rs, cur, bscan, node_attr, W_mpl, Ps, Pd);
    hipLaunchKernelGGL(gbounds_kernel, dim3(ngrid), dim3(256), 0, stream, batch, gstart);
    hipLaunchKernelGGL(pe_quad_kernel, dim3(egrid), dim3(256), 0, stream,
                       ei, edge_attr, W_mpl, b_mpl, Ps, cur, PeP);
    hipLaunchKernelGGL(agg_kernel, dim3((NODES + 63) / 64), dim3(256), 0, stream,
                       rs, PeP, Pd, W1, b1, W2, b2, x2);
    hipLaunchKernelGGL(graph2_kernel, dim3(GRAPHS), dim3(64), 0, stream,
                       gstart, x2, W3, b3, W4, b4, out);
}

// Round 13
// 146.014 us; speedup vs baseline: 2.0252x; 1.0956x over previous
//
#include <hip/hip_runtime.h>
#include <hip/hip_fp16.h>

#define DF 64
#define MSG 20
#define HID2 10
#define NODES 50000
#define EDGES 800000
#define GRAPHS 512
#define RSTRIDE 32   // halves per padded PeP row = 64 B (one cache line)
#define RS2 12       // floats per padded x2 row = 48 B (16B-aligned)
#define NB1 ((NODES + 255) / 256)   // 196
#define WR2 12       // half2 per W row in LDS (10 data + 2 pad) = 48 B

// 20 FMAs: acc[0..19] += xv * wr[0..19] (wr points into LDS, 16B-aligned)
#define FMA20(acc, xv, wr) do { \
  float4 w0_ = *(const float4*)((wr) + 0);  float4 w1_ = *(const float4*)((wr) + 4); \
  float4 w2_ = *(const float4*)((wr) + 8);  float4 w3_ = *(const float4*)((wr) + 12); \
  float4 w4_ = *(const float4*)((wr) + 16); \
  acc[0]=fmaf(xv,w0_.x,acc[0]);  acc[1]=fmaf(xv,w0_.y,acc[1]);  acc[2]=fmaf(xv,w0_.z,acc[2]);  acc[3]=fmaf(xv,w0_.w,acc[3]); \
  acc[4]=fmaf(xv,w1_.x,acc[4]);  acc[5]=fmaf(xv,w1_.y,acc[5]);  acc[6]=fmaf(xv,w1_.z,acc[6]);  acc[7]=fmaf(xv,w1_.w,acc[7]); \
  acc[8]=fmaf(xv,w2_.x,acc[8]);  acc[9]=fmaf(xv,w2_.y,acc[9]);  acc[10]=fmaf(xv,w2_.z,acc[10]); acc[11]=fmaf(xv,w2_.w,acc[11]); \
  acc[12]=fmaf(xv,w3_.x,acc[12]); acc[13]=fmaf(xv,w3_.y,acc[13]); acc[14]=fmaf(xv,w3_.z,acc[14]); acc[15]=fmaf(xv,w3_.w,acc[15]); \
  acc[16]=fmaf(xv,w4_.x,acc[16]); acc[17]=fmaf(xv,w4_.y,acc[17]); acc[18]=fmaf(xv,w4_.z,acc[18]); acc[19]=fmaf(xv,w4_.w,acc[19]); \
} while (0)

__global__ __launch_bounds__(256) void zero_cnt_kernel(int* __restrict__ cnt) {
    int i = blockIdx.x * 256 + threadIdx.x;
    int st = gridDim.x * 256;
    for (int k = i; k < NODES; k += st) cnt[k] = 0;
}

// Counting pass; the atomic's return value IS the edge's rank within its dst.
// rank[] lets pe_quad compute its CSR slot with ZERO atomics.
__global__ __launch_bounds__(256) void count_kernel(const int* __restrict__ ei,
                                                    int* __restrict__ cnt,
                                                    int* __restrict__ rank) {
    int e = blockIdx.x * 256 + threadIdx.x;
    if (e < EDGES) rank[e] = atomicAdd(&cnt[ei[EDGES + e]], 1);
}

// Block-wise exclusive scan (Hillis-Steele in LDS).
__global__ __launch_bounds__(256) void scan_block(const int* __restrict__ in, int* __restrict__ outx,
                                                  int* __restrict__ bsum, int n) {
    __shared__ int s[256];
    int t = threadIdx.x, i = blockIdx.x * 256 + t;
    int v = (i < n) ? in[i] : 0;
    s[t] = v; __syncthreads();
    for (int off = 1; off < 256; off <<= 1) {
        int x = (t >= off) ? s[t - off] : 0;
        __syncthreads();
        s[t] += x; __syncthreads();
    }
    if (i < n) outx[i] = s[t] - v;
    if (t == 255 && bsum != nullptr) bsum[blockIdx.x] = s[255];
}

__device__ __forceinline__ void store_row_h(__half* dst, const float* acc) {
    union { __half2 h2[16]; uint4 q[4]; } u;
#pragma unroll
    for (int i = 0; i < 10; ++i) u.h2[i] = __floats2half2_rn(acc[2 * i], acc[2 * i + 1]);
#pragma unroll
    for (int i = 10; i < 16; ++i) u.h2[i] = __floats2half2_rn(0.0f, 0.0f);
    uint4* po = (uint4*)dst;
    po[0] = u.q[0]; po[1] = u.q[1]; po[2] = u.q[2]; po[3] = u.q[3];
}

// Fused: scan fixup (rs += bscan) + gbounds (batch sorted -> graph ranges) + pn projections.
__global__ __launch_bounds__(256) void fixup_pn_kernel(int* __restrict__ rs,
                                                       const int* __restrict__ bscan,
                                                       const int* __restrict__ batch,
                                                       int* __restrict__ gstart,
                                                       const float* __restrict__ node_attr,
                                                       const float* __restrict__ W,
                                                       __half* __restrict__ Ps, __half* __restrict__ Pd) {
    int i = blockIdx.x * 256 + threadIdx.x;
    if (i < NODES) {
        rs[i] = rs[i] + bscan[blockIdx.x];
        int b = batch[i];
        int bp = (i == 0) ? -1 : batch[i - 1];
        for (int g = bp + 1; g <= b; ++g) gstart[g] = i;
        if (i == NODES - 1) {
            for (int g = b + 1; g <= GRAPHS; ++g) gstart[g] = NODES;
        }
    }
    if (i == 0) rs[NODES] = EDGES;

    __shared__ float Wss[DF * MSG];
    __shared__ float Wds[DF * MSG];
    for (int k = threadIdx.x; k < DF * MSG; k += 256) {
        Wss[k] = W[k];
        Wds[k] = W[DF * MSG + k];
    }
    __syncthreads();

    int n = i;
    if (n >= NODES) return;

    const float4* nr = (const float4*)(node_attr + (size_t)n * DF);
    float4 x[16];
#pragma unroll
    for (int q = 0; q < 16; ++q) x[q] = nr[q];

    float as[MSG], ad[MSG];
#pragma unroll
    for (int j = 0; j < MSG; ++j) { as[j] = 0.0f; ad[j] = 0.0f; }

#pragma unroll
    for (int k4 = 0; k4 < 16; ++k4) {
        const float* xp = (const float*)&x[k4];
#pragma unroll
        for (int cc = 0; cc < 4; ++cc) {
            int k = k4 * 4 + cc;
            FMA20(as, xp[cc], &Wss[k * MSG]);
            FMA20(ad, xp[cc], &Wds[k * MSG]);
        }
    }

    store_row_h(Ps + (size_t)n * RSTRIDE, as);
    store_row_h(Pd + (size_t)n * RSTRIDE, ad);
}

__device__ __forceinline__ __half2 shflx_h2(__half2 v, int mask) {
    int x; __builtin_memcpy(&x, &v, 4);
    x = __shfl_xor(x, mask, 4);
    __half2 r; __builtin_memcpy(&r, &x, 4);
    return r;
}

// branchless 4-way select by q (0..3)
__device__ __forceinline__ __half2 sel4(int q, __half2 a, __half2 b, __half2 c, __half2 d) {
    __half2 ab = (q & 1) ? b : a;
    __half2 cd = (q & 1) ? d : c;
    return (q & 2) ? cd : ab;
}

// Edge kernel ("quad"): 4 lanes per edge, 4 edges per 4-lane group.
// CSR slot = rs[dst] + rank[e] -- NO atomics in this kernel.
__global__ __launch_bounds__(256, 4) void pe_quad_kernel(
    const int* __restrict__ ei,
    const float* __restrict__ edge_attr,
    const float* __restrict__ W, const float* __restrict__ b,
    const __half* __restrict__ Ps,
    const int* __restrict__ rs,
    const int* __restrict__ rank,
    __half* __restrict__ PeP)
{
    __shared__ __half2 Wh2[64 * WR2];   // 3072 B
    __shared__ __half2 bh[16];

    const int t = threadIdx.x;
    const int q = t & 3;
    const int e0 = blockIdx.x * 256 + (t >> 2) * 4;

    for (int i = t; i < 64 * WR2; i += 256) {
        int k = i / WR2, j = i - k * WR2;
        __half2 v = __floats2half2_rn(0.0f, 0.0f);
        if (j < 10) v = __floats2half2_rn(W[2 * DF * MSG + k * MSG + 2 * j],
                                          W[2 * DF * MSG + k * MSG + 2 * j + 1]);
        Wh2[i] = v;
    }
    if (t < 16) {
        __half2 v = __floats2half2_rn(0.0f, 0.0f);
        if (t < 10) v = __floats2half2_rn(b[2 * t], b[2 * t + 1]);
        bh[t] = v;
    }

    const int eq = e0 + q;
    const int srcq = ei[eq];
    const int dstq = ei[EDGES + eq];
    const int pq = rs[dstq] + rank[eq];   // CSR slot, atomic-free

    const float4* ea4 = (const float4*)edge_attr;
    __half2 xh[4][8];
#pragma unroll
    for (int i = 0; i < 4; ++i) {
        size_t rb = (size_t)(e0 + i) * 16 + q;
        float4 v0 = ea4[rb + 0];
        float4 v1 = ea4[rb + 4];
        float4 v2 = ea4[rb + 8];
        float4 v3 = ea4[rb + 12];
        xh[i][0] = __floats2half2_rn(v0.x, v0.y); xh[i][1] = __floats2half2_rn(v0.z, v0.w);
        xh[i][2] = __floats2half2_rn(v1.x, v1.y); xh[i][3] = __floats2half2_rn(v1.z, v1.w);
        xh[i][4] = __floats2half2_rn(v2.x, v2.y); xh[i][5] = __floats2half2_rn(v2.z, v2.w);
        xh[i][6] = __floats2half2_rn(v3.x, v3.y); xh[i][7] = __floats2half2_rn(v3.z, v3.w);
    }

    __syncthreads();

    __half2 acc[4][10];
#pragma unroll
    for (int i = 0; i < 4; ++i)
#pragma unroll
        for (int j = 0; j < 10; ++j) acc[i][j] = __floats2half2_rn(0.0f, 0.0f);

#pragma unroll
    for (int s = 0; s < 4; ++s) {
#pragma unroll
        for (int d = 0; d < 2; ++d) {
#pragma unroll
            for (int lh = 0; lh < 2; ++lh) {
                int k = s * 16 + q * 4 + 2 * d + lh;
                const __half2* wr = Wh2 + k * WR2;
                __half2 wa[10];
#pragma unroll
                for (int j = 0; j < 10; ++j) wa[j] = wr[j];
#pragma unroll
                for (int i = 0; i < 4; ++i) {
                    __half2 xb = lh ? __high2half2(xh[i][s * 2 + d])
                                    : __low2half2(xh[i][s * 2 + d]);
#pragma unroll
                    for (int j = 0; j < 10; ++j)
                        acc[i][j] = __hfma2(xb, wa[j], acc[i][j]);
                }
            }
        }
    }

#pragma unroll
    for (int i = 0; i < 4; ++i)
#pragma unroll
        for (int j = 0; j < 10; ++j) {
            acc[i][j] = __hadd2(acc[i][j], shflx_h2(acc[i][j], 1));
            acc[i][j] = __hadd2(acc[i][j], shflx_h2(acc[i][j], 2));
        }

#pragma unroll
    for (int i = 0; i < 4; ++i)
#pragma unroll
        for (int j = 0; j < 10; ++j) acc[i][j] = __hadd2(acc[i][j], bh[j]);

    const __half2 hz = __floats2half2_rn(0.0f, 0.0f);
#pragma unroll
    for (int i = 0; i < 4; ++i) {
        int pi = __shfl(pq, i, 4);
        int si = __shfl(srcq, i, 4);

        __half2 o0 = sel4(q, acc[i][0], acc[i][4], acc[i][8], hz);
        __half2 o1 = sel4(q, acc[i][1], acc[i][5], acc[i][9], hz);
        __half2 o2 = sel4(q, acc[i][2], acc[i][6], hz,        hz);
        __half2 o3 = sel4(q, acc[i][3], acc[i][7], hz,        hz);

        uint4 ps = *(const uint4*)(Ps + (size_t)si * RSTRIDE + q * 8);
        union { uint4 u; __half2 h[4]; } pu; pu.u = ps;
        union { uint4 u; __half2 h[4]; } ou;
        ou.h[0] = __hadd2(o0, pu.h[0]);
        ou.h[1] = __hadd2(o1, pu.h[1]);
        ou.h[2] = __hadd2(o2, pu.h[2]);
        ou.h[3] = __hadd2(o3, pu.h[3]);

        *(uint4*)(PeP + (size_t)pi * RSTRIDE + q * 8) = ou.u;
    }
}

// Node aggregate: 4 lanes/node, 4-deep UNCONDITIONAL (index-clamped) load batching,
// guards only on the accumulate. x2 store, no atomics.
__global__ __launch_bounds__(256, 4) void agg_kernel(const int* __restrict__ rs,
                                                     const __half* __restrict__ PeP,
                                                     const __half* __restrict__ Pd,
                                                     const float* __restrict__ W1, const float* __restrict__ b1,
                                                     const float* __restrict__ W2, const float* __restrict__ b2,
                                                     float* __restrict__ x2) {
    __shared__ float W1s[MSG * MSG], W2s[MSG * HID2], b1s[MSG], b2s[HID2];
    for (int i = threadIdx.x; i < MSG * MSG; i += 256) W1s[i] = W1[i];
    for (int i = threadIdx.x; i < MSG * HID2; i += 256) W2s[i] = W2[i];
    if (threadIdx.x < MSG) b1s[threadIdx.x] = b1[threadIdx.x];
    if (threadIdx.x < HID2) b2s[threadIdx.x] = b2[threadIdx.x];
    __syncthreads();

    int t = threadIdx.x;
    int node = blockIdx.x * 64 + (t >> 2);
    int lane = t & 3;

    float acc[MSG];
#pragma unroll
    for (int j = 0; j < MSG; ++j) acc[j] = 0.0f;

    if (node < NODES) {
        int s0 = rs[node];
        int deg = rs[node + 1] - s0;

        float pd[MSG];
        {
            const uint4* pr = (const uint4*)(Pd + (size_t)node * RSTRIDE);
            union { uint4 q; __half2 h2[4]; } a0, a1;
            union { uint2 q; __half2 h2[2]; } a2;
            a0.q = pr[0]; a1.q = pr[1]; a2.q = *(const uint2*)(pr + 2);
#pragma unroll
            for (int i = 0; i < 4; ++i) {
                float2 f = __half22float2(a0.h2[i]);
                pd[2 * i] = f.x; pd[2 * i + 1] = f.y;
            }
#pragma unroll
            for (int i = 0; i < 4; ++i) {
                float2 f = __half22float2(a1.h2[i]);
                pd[8 + 2 * i] = f.x; pd[9 + 2 * i] = f.y;
            }
#pragma unroll
            for (int i = 0; i < 2; ++i) {
                float2 f = __half22float2(a2.h2[i]);
                pd[16 + 2 * i] = f.x; pd[17 + 2 * i] = f.y;
            }
        }

        for (int i0 = lane; i0 < deg; i0 += 16) {
            uint4 qa[4], qb[4]; uint2 qc[4]; int vm[4];
#pragma unroll
            for (int u = 0; u < 4; ++u) {
                int i = i0 + 4 * u;
                vm[u] = (i < deg);
                int ii = vm[u] ? i : 0;           // clamped: load always issues
                const uint4* rp = (const uint4*)(PeP + (size_t)(s0 + ii) * RSTRIDE);
                qa[u] = rp[0]; qb[u] = rp[1]; qc[u] = *(const uint2*)(rp + 2);
            }
#pragma unroll
            for (int u = 0; u < 4; ++u) {
                if (!vm[u]) continue;
                union { uint4 q; __half2 h2[4]; } a0, a1;
                union { uint2 q; __half2 h2[2]; } a2;
                a0.q = qa[u]; a1.q = qb[u]; a2.q = qc[u];
#pragma unroll
                for (int k = 0; k < 4; ++k) {
                    float2 f = __half22float2(a0.h2[k]);
                    acc[2 * k]     += fmaxf(f.x + pd[2 * k], 0.0f);
                    acc[2 * k + 1] += fmaxf(f.y + pd[2 * k + 1], 0.0f);
                }
#pragma unroll
                for (int k = 0; k < 4; ++k) {
                    float2 f = __half22float2(a1.h2[k]);
                    acc[8 + 2 * k] += fmaxf(f.x + pd[8 + 2 * k], 0.0f);
                    acc[9 + 2 * k] += fmaxf(f.y + pd[9 + 2 * k], 0.0f);
                }
#pragma unroll
                for (int k = 0; k < 2; ++k) {
                    float2 f = __half22float2(a2.h2[k]);
                    acc[16 + 2 * k] += fmaxf(f.x + pd[16 + 2 * k], 0.0f);
                    acc[17 + 2 * k] += fmaxf(f.y + pd[17 + 2 * k], 0.0f);
                }
            }
        }
    }

#pragma unroll
    for (int j = 0; j < MSG; ++j) acc[j] += __shfl_xor(acc[j], 1);
#pragma unroll
    for (int j = 0; j < MSG; ++j) acc[j] += __shfl_xor(acc[j], 2);

    if (node < NODES && lane == 0) {
        float t1[MSG];
#pragma unroll
        for (int j = 0; j < MSG; ++j) t1[j] = b1s[j];
#pragma unroll
        for (int k = 0; k < MSG; ++k)
#pragma unroll
            for (int j = 0; j < MSG; ++j) t1[j] = fmaf(acc[k], W1s[k * MSG + j], t1[j]);
#pragma unroll
        for (int j = 0; j < MSG; ++j) t1[j] = fmaxf(t1[j], 0.0f);

        float t2[HID2];
#pragma unroll
        for (int m = 0; m < HID2; ++m) t2[m] = b2s[m];
#pragma unroll
        for (int k = 0; k < MSG; ++k)
#pragma unroll
            for (int m = 0; m < HID2; ++m) t2[m] = fmaf(t1[k], W2s[k * HID2 + m], t2[m]);

        float* xo = x2 + (size_t)node * RS2;
        *(float4*)(xo)     = make_float4(fmaxf(t2[0], 0.f), fmaxf(t2[1], 0.f), fmaxf(t2[2], 0.f), fmaxf(t2[3], 0.f));
        *(float4*)(xo + 4) = make_float4(fmaxf(t2[4], 0.f), fmaxf(t2[5], 0.f), fmaxf(t2[6], 0.f), fmaxf(t2[7], 0.f));
        *(float4*)(xo + 8) = make_float4(fmaxf(t2[8], 0.f), fmaxf(t2[9], 0.f), 0.f, 0.f);
    }
}

// Graph reduce: one 64-thread wave per graph streams its CONTIGUOUS x2 segment.
__global__ __launch_bounds__(64) void graph2_kernel(const int* __restrict__ gstart,
                                                    const float* __restrict__ x2,
                                                    const float* __restrict__ W3, const float* __restrict__ b3,
                                                    const float* __restrict__ W4, const float* __restrict__ b4,
                                                    float* __restrict__ out) {
    int g = blockIdx.x;
    int lane = threadIdx.x;
    int n0 = gstart[g], n1 = gstart[g + 1];

    float acc[HID2];
#pragma unroll
    for (int j = 0; j < HID2; ++j) acc[j] = 0.0f;

    for (int i = n0 + lane; i < n1; i += 64) {
        const float* xr = x2 + (size_t)i * RS2;
        float4 v0 = *(const float4*)xr;
        float4 v1 = *(const float4*)(xr + 4);
        float2 v2 = *(const float2*)(xr + 8);
        acc[0] += v0.x; acc[1] += v0.y; acc[2] += v0.z; acc[3] += v0.w;
        acc[4] += v1.x; acc[5] += v1.y; acc[6] += v1.z; acc[7] += v1.w;
        acc[8] += v2.x; acc[9] += v2.y;
    }

#pragma unroll
    for (int m = 1; m < 64; m <<= 1)
#pragma unroll
        for (int j = 0; j < HID2; ++j) acc[j] += __shfl_xor(acc[j], m);

    if (lane == 0) {
        float tt[HID2];
#pragma unroll
        for (int j = 0; j < HID2; ++j) {
            float s = b3[j];
#pragma unroll
            for (int k = 0; k < HID2; ++k) s = fmaf(acc[k], W3[k * HID2 + j], s);
            tt[j] = fmaxf(s, 0.0f);
        }
        float s = b4[0];
#pragma unroll
        for (int k = 0; k < HID2; ++k) s = fmaf(tt[k], W4[k], s);
        out[g] = s;
    }
}

extern "C" void kernel_launch(void* const* d_in, const int* in_sizes, int n_in,
                              void* d_out, int out_size, void* d_ws, size_t ws_size,
                              hipStream_t stream) {
    const int*   ei        = (const int*)  d_in[0];
    const float* node_attr = (const float*)d_in[1];
    const float* edge_attr = (const float*)d_in[2];
    const int*   batch     = (const int*)  d_in[3];
    const float* W_mpl     = (const float*)d_in[4];
    const float* b_mpl     = (const float*)d_in[5];
    const float* W1        = (const float*)d_in[6];
    const float* b1        = (const float*)d_in[7];
    const float* W2        = (const float*)d_in[8];
    const float* b2        = (const float*)d_in[9];
    const float* W3        = (const float*)d_in[10];
    const float* b3        = (const float*)d_in[11];
    const float* W4        = (const float*)d_in[12];
    const float* b4        = (const float*)d_in[13];
    float* out = (float*)d_out;

    // workspace layout (all offsets multiples of 64B)
    __half* PeP = (__half*)d_ws;                          // E*32 halves (51.2 MB), CSR-ordered
    __half* Ps  = PeP + (size_t)EDGES * RSTRIDE;          // N*32 halves (3.2 MB)
    __half* Pd  = Ps + (size_t)NODES * RSTRIDE;           // N*32 halves (3.2 MB)
    float* x2   = (float*)(Pd + (size_t)NODES * RSTRIDE); // N*12 floats (2.4 MB)
    int* cnt    = (int*)(x2 + (size_t)NODES * RS2);       // N (padded 50176)
    int* rs     = cnt + 50176;                            // N+1 (padded)
    int* rank   = rs + 50176;                             // E (3.2 MB)
    int* bsum   = rank + EDGES;                           // 256
    int* bscan  = bsum + 256;                             // 256
    int* gstart = bscan + 256;                            // G+1

    int egrid  = (EDGES + 255) / 256;   // 3125
    int ngrid  = NB1;                   // 196

    hipLaunchKernelGGL(zero_cnt_kernel, dim3(256), dim3(256), 0, stream, cnt);
    hipLaunchKernelGGL(count_kernel, dim3(egrid), dim3(256), 0, stream, ei, cnt, rank);
    hipLaunchKernelGGL(scan_block, dim3(ngrid), dim3(256), 0, stream, cnt, rs, bsum, NODES);
    hipLaunchKernelGGL(scan_block, dim3(1), dim3(256), 0, stream, bsum, bscan, (int*)nullptr, NB1);
    hipLaunchKernelGGL(fixup_pn_kernel, dim3(ngrid), dim3(256), 0, stream,
                       rs, bscan, batch, gstart, node_attr, W_mpl, Ps, Pd);
    hipLaunchKernelGGL(pe_quad_kernel, dim3(egrid), dim3(256), 0, stream,
                       ei, edge_attr, W_mpl, b_mpl, Ps, rs, rank, PeP);
    hipLaunchKernelGGL(agg_kernel, dim3((NODES + 63) / 64), dim3(256), 0, stream,
                       rs, PeP, Pd, W1, b1, W2, b2, x2);
    hipLaunchKernelGGL(graph2_kernel, dim3(GRAPHS), dim3(64), 0, stream,
                       gstart, x2, W3, b3, W4, b4, out);
}